// Round 11
// baseline (297.954 us; speedup 1.0000x reference)
//
#include <hip/hip_runtime.h>
#include <math.h>

#define NB 4
#define NC 64
#define NL 1024   // 32x32 kernel-patch grid
#define NP 3969   // 63x63 correlation positions
#define PHW 63

typedef unsigned short ushort_t;
typedef __attribute__((ext_vector_type(8))) short short8;
typedef __attribute__((ext_vector_type(16))) float floatx16;

// A' per b: 32 rtiles * 64 kchunks * 64 lanes * 8 = 2^20 ushorts
#define A_BSTRIDE 1048576
// B' per b: 128 rtiles (4096 rows, padded for 256-wide p-tiles) * 64 * 512
#define B_BSTRIDE 4194304

// ---------------- kernel 1: fused prep = norm + stats + padB --------------
// blocks 0..255   : per-(b,c) inverse L2 norm of b
// blocks 256..334 : patch means of (1-mask) -> mmk, mmp
// blocks 335..846 : zero B' pad rows 3968..4095 (rtiles 124..127)
__global__ __launch_bounds__(256) void prep_kernel(const float* __restrict__ bsrc,
                                                   const float* __restrict__ mask,
                                                   float* __restrict__ invn,
                                                   float* __restrict__ mmk,
                                                   float* __restrict__ mmp,
                                                   ushort_t* __restrict__ Bhi,
                                                   ushort_t* __restrict__ Blo) {
    int blk = blockIdx.x;
    if (blk < 256) {
        const float* src = bsrc + (size_t)blk * 4096;
        float s = 0.f;
        for (int i = threadIdx.x; i < 4096; i += 256) { float v = src[i]; s += v * v; }
#pragma unroll
        for (int off = 32; off > 0; off >>= 1) s += __shfl_down(s, off, 64);
        __shared__ float part[4];
        if ((threadIdx.x & 63) == 0) part[threadIdx.x >> 6] = s;
        __syncthreads();
        if (threadIdx.x == 0) {
            float t = part[0] + part[1] + part[2] + part[3];
            invn[blk] = 1.0f / sqrtf(t + 1e-8f);
        }
    } else if (blk < 335) {
        int id = (blk - 256) * 256 + threadIdx.x;
        if (id < NB * NL) {
            int b = id >> 10, l = id & 1023;
            int lh = l >> 5, lw = l & 31;
            const float* m = mask + b * 4096;
            float s = 0.f;
#pragma unroll
            for (int i = 0; i < 4; ++i) {
                int r = min(max(2 * lh - 1 + i, 0), 63);
#pragma unroll
                for (int j = 0; j < 4; ++j) {
                    int c = min(max(2 * lw - 1 + j, 0), 63);
                    s += 1.0f - m[r * 64 + c];
                }
            }
            mmk[id] = s * (1.0f / 16.0f);
        } else {
            int id2 = id - NB * NL;
            if (id2 < NB * NP) {
                int b = id2 / NP, p = id2 - b * NP;
                int ph = p / PHW, pw = p - ph * PHW;
                const float* m = mask + b * 4096;
                float s = 0.f;
#pragma unroll
                for (int i = 0; i < 4; ++i) {
                    int r = min(max(ph - 1 + i, 0), 63);
#pragma unroll
                    for (int j = 0; j < 4; ++j) {
                        int c = min(max(pw - 1 + j, 0), 63);
                        s += 1.0f - m[r * 64 + c];
                    }
                }
                mmp[id2] = s * (1.0f / 16.0f);
            }
        }
    } else {
        // zero rtiles 124..127 (rows 3968..4095) for all b, both matrices
        int idx = (blk - 335) * 256 + threadIdx.x;   // 0..131071
        int b = idx >> 15;
        int r = idx & 32767;
        int mat = r >> 14;
        int o = r & 16383;
        ushort_t* base = (mat ? Blo : Bhi) + (size_t)b * B_BSTRIDE + 124 * 32768;
        uint4 z = {0u, 0u, 0u, 0u};
        ((uint4*)base)[o] = z;
    }
}

// ------------- split helper: fp32 -> bf16 hi + bf16 residual --------------
__device__ inline void split_bf16(float v, ushort_t& hv, ushort_t& lv) {
    unsigned u = __float_as_uint(v);
    unsigned rr = u + 0x7FFFu + ((u >> 16) & 1u);
    hv = (ushort_t)(rr >> 16);
    float fh = __uint_as_float(((unsigned)hv) << 16);
    float remv = v - fh;
    unsigned u2 = __float_as_uint(remv);
    unsigned rr2 = u2 + 0x7FFFu + ((u2 >> 16) & 1u);
    lv = (ushort_t)(rr2 >> 16);
}

// fragment-order address for (row, kchunk)
__device__ inline int frag_addr(int row, int kc) {
    return ((row >> 5) * 64 + kc) * 512 + (row & 31) * 8;
}

// --------- kernel 3: merged splitA (x<32) + splitB (x>=32) ---------------
__global__ __launch_bounds__(256) void split_kernel(const float* __restrict__ bsrc,
                                                    const float* __restrict__ invn,
                                                    ushort_t* __restrict__ Ahi,
                                                    ushort_t* __restrict__ Alo,
                                                    const float* __restrict__ fsrc,
                                                    ushort_t* __restrict__ Bhi,
                                                    ushort_t* __restrict__ Blo) {
    __shared__ float fl[32 * 257];
    int x = blockIdx.x, b = blockIdx.y, chalf = blockIdx.z;
    int t = threadIdx.x;
    if (x < 32) {
        int lh = x;
#pragma unroll
        for (int q = 0; q < 32; ++q) {
            int idx = t + (q << 8);
            int cl = idx >> 8, rem = idx & 255;
            int i = rem >> 6, s = rem & 63;
            int c = (chalf << 5) + cl;
            int r = min(max(2 * lh - 1 + i, 0), 63);
            fl[cl * 257 + rem] = bsrc[(((size_t)((b << 6) + c)) << 12) + (r << 6) + s];
        }
        __syncthreads();
        ushort_t* Ah = Ahi + (size_t)b * A_BSTRIDE;
        ushort_t* Al = Alo + (size_t)b * A_BSTRIDE;
#pragma unroll
        for (int q = 0; q < 4; ++q) {
            int pair = t + (q << 8);         // 0..1023
            int lw = pair & 31, cl = pair >> 5;
            int c = (chalf << 5) + cl;
            float scale = invn[(b << 6) + c];
            const float* row = fl + cl * 257;
            __align__(16) ushort_t h[16];
            __align__(16) ushort_t lo[16];
#pragma unroll
            for (int i = 0; i < 4; ++i)
#pragma unroll
                for (int j = 0; j < 4; ++j) {
                    int s = min(max(2 * lw - 1 + j, 0), 63);
                    split_bf16(row[i * 64 + s] * scale, h[i * 4 + j], lo[i * 4 + j]);
                }
            int a = (lh * 64 + c) * 512 + lw * 8;
            *(uint4*)(Ah + a)       = *(uint4*)h;
            *(uint4*)(Ah + a + 256) = *(uint4*)(h + 8);
            *(uint4*)(Al + a)       = *(uint4*)lo;
            *(uint4*)(Al + a + 256) = *(uint4*)(lo + 8);
        }
    } else {
        int ph = x - 32;
#pragma unroll
        for (int q = 0; q < 32; ++q) {
            int idx = t + (q << 8);
            int cl = idx >> 8, rem = idx & 255;
            int i = rem >> 6, s = rem & 63;
            int c = (chalf << 5) + cl;
            int r = min(max(ph - 1 + i, 0), 63);
            fl[cl * 257 + rem] = fsrc[(((size_t)((b << 6) + c)) << 12) + (r << 6) + s];
        }
        __syncthreads();
        ushort_t* Bh = Bhi + (size_t)b * B_BSTRIDE;
        ushort_t* Bl = Blo + (size_t)b * B_BSTRIDE;
#pragma unroll
        for (int q = 0; q < 8; ++q) {
            int pair = t + (q << 8);          // 0..2047
            int pw = pair & 63, cl = pair >> 6;
            if (pw < PHW) {
                int c = (chalf << 5) + cl;
                const float* row = fl + cl * 257;
                __align__(16) ushort_t h[16];
                __align__(16) ushort_t lo[16];
#pragma unroll
                for (int i = 0; i < 4; ++i)
#pragma unroll
                    for (int j = 0; j < 4; ++j) {
                        int s = min(max(pw - 1 + j, 0), 63);
                        split_bf16(row[i * 64 + s], h[i * 4 + j], lo[i * 4 + j]);
                    }
                int p = ph * PHW + pw;
                int a = frag_addr(p, c);
                *(uint4*)(Bh + a)       = *(uint4*)h;
                *(uint4*)(Bh + a + 256) = *(uint4*)(h + 8);
                *(uint4*)(Bl + a)       = *(uint4*)lo;
                *(uint4*)(Bl + a + 256) = *(uint4*)(lo + 8);
            }
        }
    }
}

// ------------- kernel 4: 128x256-tile, 4-wave, 2-blocks/CU GEMM -----------
// (unchanged from Round 8: 51% MfmaUtil, 90 us — control for this round)
__global__ __launch_bounds__(256, 2) void gemm_kernel(
    const ushort_t* __restrict__ Ahi, const ushort_t* __restrict__ Alo,
    const ushort_t* __restrict__ Bhi, const ushort_t* __restrict__ Blo,
    float* __restrict__ Rt) {
    // [buf][12288 elems]: Ahi(4x512) Alo(4x512) Bhi(8x512) Blo(8x512) = 24KB
    __shared__ ushort_t smem[2][12288];
    int tid = threadIdx.x;
    int lane = tid & 63, w = tid >> 6;         // w = 0..3 (p-wave)
    int bid = blockIdx.x;                      // 0..511
    int wid = ((bid & 7) << 6) + (bid >> 3);   // bijective XCD-chunk remap
    int b = wid >> 7;
    int rem = wid & 127;
    int lg = rem >> 4;                         // 0..7  : L0 = lg*128
    int pg = rem & 15;                         // 0..15 : P0 = pg*256
    int L0 = lg << 7, P0 = pg << 8;

    // stage roles: 24 segments of 512 elems per chunk, wave w owns 6.
    const ushort_t* segp[6];
    int seg0 = w * 6;
#pragma unroll
    for (int i = 0; i < 6; ++i) {
        int seg = seg0 + i;
        const ushort_t* base;
        int rt;
        if (seg < 4)       { base = Ahi + (size_t)b * A_BSTRIDE + (size_t)(lg << 2) * 32768; rt = seg; }
        else if (seg < 8)  { base = Alo + (size_t)b * A_BSTRIDE + (size_t)(lg << 2) * 32768; rt = seg - 4; }
        else if (seg < 16) { base = Bhi + (size_t)b * B_BSTRIDE + (size_t)(pg << 3) * 32768; rt = seg - 8; }
        else               { base = Blo + (size_t)b * B_BSTRIDE + (size_t)(pg << 3) * 32768; rt = seg - 16; }
        segp[i] = base + (size_t)rt * 32768 + (size_t)(lane << 3);
    }
    int dst0 = seg0 * 512;                     // wave-uniform LDS elem offset

    ushort_t* buf0 = smem[0];
    ushort_t* buf1 = smem[1];

#define STAGE(dstp, kc)                                                                    \
    do {                                                                                   \
        _Pragma("unroll")                                                                  \
        for (int i = 0; i < 6; ++i)                                                        \
            __builtin_amdgcn_global_load_lds(                                              \
                (const __attribute__((address_space(1))) void*)(segp[i] + (size_t)(kc) * 512), \
                (__attribute__((address_space(3))) void*)((dstp) + dst0 + i * 512),        \
                16, 0, 0);                                                                 \
    } while (0)

    floatx16 acc[2][4];
#pragma unroll
    for (int i = 0; i < 2; ++i)
#pragma unroll
        for (int j = 0; j < 4; ++j)
#pragma unroll
            for (int r = 0; r < 16; ++r) acc[i][j][r] = 0.f;

    STAGE(buf0, 0);
    ushort_t* cur = buf0;
    ushort_t* nxt = buf1;

    int boff0 = 4096 + (w << 1) * 512;         // Bhi rtile base for this wave

    for (int t = 0; t < 64; ++t) {
        asm volatile("" ::: "memory");
        __builtin_amdgcn_s_barrier();            // B1: all reads of buf[nxt] done
        asm volatile("" ::: "memory");
        if (t < 63) {
            STAGE(nxt, t + 1);                   // 6 loads into the freed buffer
            asm volatile("s_waitcnt vmcnt(6)" ::: "memory");   // chunk t landed
        } else {
            asm volatile("s_waitcnt vmcnt(0)" ::: "memory");
        }
        __builtin_amdgcn_s_barrier();            // B2: chunk t visible to all
        asm volatile("" ::: "memory");

        const ushort_t* rb = cur + (lane << 3);
        short8 ah[4], al[4], bh[2], bl[2];
#pragma unroll
        for (int lt = 0; lt < 4; ++lt) {
            ah[lt] = *(const short8*)(rb + lt * 512);
            al[lt] = *(const short8*)(rb + 2048 + lt * 512);
        }
#pragma unroll
        for (int pt = 0; pt < 2; ++pt) {
            bh[pt] = *(const short8*)(rb + boff0 + pt * 512);
            bl[pt] = *(const short8*)(rb + 4096 + boff0 + pt * 512);
        }
        __builtin_amdgcn_s_setprio(1);
#pragma unroll
        for (int pt = 0; pt < 2; ++pt)
#pragma unroll
            for (int lt = 0; lt < 4; ++lt) {
                acc[pt][lt] = __builtin_amdgcn_mfma_f32_32x32x16_bf16(bh[pt], ah[lt], acc[pt][lt], 0, 0, 0);
                acc[pt][lt] = __builtin_amdgcn_mfma_f32_32x32x16_bf16(bh[pt], al[lt], acc[pt][lt], 0, 0, 0);
                acc[pt][lt] = __builtin_amdgcn_mfma_f32_32x32x16_bf16(bl[pt], ah[lt], acc[pt][lt], 0, 0, 0);
            }
        __builtin_amdgcn_s_setprio(0);
        ushort_t* tmp = cur; cur = nxt; nxt = tmp;
    }
#undef STAGE

    int x = lane & 31, kg = lane >> 5;
    int pw0 = P0 + (w << 6);
#pragma unroll
    for (int pt = 0; pt < 2; ++pt)
#pragma unroll
        for (int lt = 0; lt < 4; ++lt)
#pragma unroll
            for (int r = 0; r < 16; ++r) {
                int p = pw0 + (pt << 5) + (r & 3) + ((r >> 2) << 3) + (kg << 2);
                int l = L0 + (lt << 5) + x;
                if (p < NP) Rt[((size_t)b * NP + p) * NL + l] = acc[pt][lt][r];
            }
}

// ------- kernel 5: fused diag1 + diag2 + mask + softmax, row output -------
// Each block handles 7 consecutive p (same ph row) so the BUILD row reads
// (p±1, Pm±1, Pp±1 chains advance by 1 per iteration) hit L1/L2: traffic
// (9+6x3)/7 = 3.9 rows/p vs 9 rows/p, blocks 15876 -> 2268. Per-p math is
// bit-identical to the verified per-p kernel.
__global__ __launch_bounds__(256) void softmax_fused_kernel(const float* __restrict__ Rt,
                                                            const float* __restrict__ mmkA,
                                                            const float* __restrict__ mmpA,
                                                            float* __restrict__ E) {
    __shared__ float ld0[1024], ld1[1024], ld2[1024];
    __shared__ float red[8];
    int ph = blockIdx.x, pwg = blockIdx.y, b = blockIdx.z;
    int t = threadIdx.x;
    int lane = t & 63, w = t >> 6;
    int l0 = t << 2;
    const float* Rb = Rt + (size_t)b * NP * NL;

    for (int g = 0; g < 7; ++g) {
        int pw = pwg * 7 + g;
        int p = ph * PHW + pw;
        bool okm = (p != 0), okp = (p != 3968);
        int Pm = (ph > 0) ? p - 63 : 3905 + pw;
        int Pp = (ph < 62) ? p + 63 : pw + 1;

#define BUILD(dst, q)                                                   \
    do {                                                                \
        const float* base = Rb + (size_t)(q) * NL;                      \
        float4 r = *(const float4*)(base + l0);                         \
        if ((q) > 0) {                                                  \
            const float* pm = base - NL;                                \
            r.x += (l0 > 0) ? pm[l0 - 1] : 0.f;                         \
            r.y += pm[l0];  r.z += pm[l0 + 1];  r.w += pm[l0 + 2];      \
        }                                                               \
        if ((q) < NP - 1) {                                             \
            const float* pp = base + NL;                                \
            r.x += pp[l0 + 1];  r.y += pp[l0 + 2];  r.z += pp[l0 + 3];  \
            r.w += (l0 + 4 < NL) ? pp[l0 + 4] : 0.f;                    \
        }                                                               \
        *(float4*)(dst + l0) = r;                                       \
    } while (0)

        BUILD(ld0, p);
        if (okm) BUILD(ld1, Pm);
        if (okp) BUILD(ld2, Pp);
#undef BUILD
        __syncthreads();

        float4 vc = *(const float4*)(ld0 + l0);
        float4 vm = {0.f, 0.f, 0.f, 0.f}, vp = {0.f, 0.f, 0.f, 0.f};
        if (okm) {
            if (l0 >= 32) vm = *(const float4*)(ld1 + l0 - 32);
            else {
                vm.x = (l0 == 0) ? 0.f : ld1[l0 + 991];
                vm.y = ld1[l0 + 992];
                vm.z = ld1[l0 + 993];
                vm.w = ld1[l0 + 994];
            }
        }
        if (okp) {
            if (l0 < 992) vp = *(const float4*)(ld2 + l0 + 32);
            else {
                vp.x = ld2[l0 - 991];
                vp.y = ld2[l0 - 990];
                vp.z = ld2[l0 - 989];
                vp.w = (l0 + 3 == 1023) ? 0.f : ld2[l0 - 988];
            }
        }
        float mmpv = mmpA[b * NP + p];
        float4 km = *(const float4*)(mmkA + b * NL + l0);
        float lg[4];
        float fsum[4] = {vc.x + vm.x + vp.x, vc.y + vm.y + vp.y,
                         vc.z + vm.z + vp.z, vc.w + vm.w + vp.w};
        float kk[4] = {km.x, km.y, km.z, km.w};
#pragma unroll
        for (int i = 0; i < 4; ++i) {
            float mmv = (((kk[i] > mmpv) && (mmpv > 0.5f)) || (kk[i] == 1.0f)) ? 1.0f : 0.0f;
            lg[i] = fsum[i] * mmv * 10.0f;
        }
        float mx = fmaxf(fmaxf(lg[0], lg[1]), fmaxf(lg[2], lg[3]));
#pragma unroll
        for (int off = 32; off >= 1; off >>= 1) mx = fmaxf(mx, __shfl_xor(mx, off, 64));
        if (lane == 0) red[w] = mx;
        __syncthreads();
        mx = fmaxf(fmaxf(red[0], red[1]), fmaxf(red[2], red[3]));
        float e[4];
        float s = 0.f;
#pragma unroll
        for (int i = 0; i < 4; ++i) { e[i] = expf(lg[i] - mx); s += e[i]; }
#pragma unroll
        for (int off = 32; off >= 1; off >>= 1) s += __shfl_xor(s, off, 64);
        if (lane == 0) red[4 + w] = s;
        __syncthreads();
        float rinv = 1.0f / (red[4] + red[5] + red[6] + red[7]);
        float4 ev = {e[0] * rinv, e[1] * rinv, e[2] * rinv, e[3] * rinv};
        *(float4*)(E + (((size_t)b * NP + p) << 10) + l0) = ev;
        __syncthreads();   // ld*/red reuse fence before next iteration's BUILD
    }
}

// ---------------- kernel 6: tiled transpose E[p][l] -> out[l][p] ----------
__global__ __launch_bounds__(256) void transpose_kernel(const float* __restrict__ E,
                                                        float* __restrict__ out) {
    __shared__ float tile[63 * 65];
    int pt = blockIdx.x;       // 0..62 : p0 = pt*63
    int lt = blockIdx.y;       // 0..15 : l0 = lt*64
    int b  = blockIdx.z;
    int t = threadIdx.x;
    int p0 = pt * 63, l0 = lt << 6;
    const float* Eb = E + ((size_t)b * NP << 10);
    {
        int j = t & 63, i4 = t >> 6;
#pragma unroll
        for (int k = 0; k < 16; ++k) {
            int i = (k << 2) + i4;
            if (i < 63) tile[i * 65 + j] = Eb[((size_t)(p0 + i) << 10) + l0 + j];
        }
    }
    __syncthreads();
    {
        int ii = t & 63, jj4 = t >> 6;
        if (ii < 63) {
#pragma unroll
            for (int k = 0; k < 16; ++k) {
                int jj = (k << 2) + jj4;
                out[((size_t)b * NL + l0 + jj) * NP + p0 + ii] = tile[ii * 65 + jj];
            }
        }
    }
}

extern "C" void kernel_launch(void* const* d_in, const int* in_sizes, int n_in,
                              void* d_out, int out_size, void* d_ws, size_t ws_size,
                              hipStream_t stream) {
    const float* f    = (const float*)d_in[0];
    const float* b    = (const float*)d_in[1];
    const float* mask = (const float*)d_in[2];
    float* out = (float*)d_out;

    // Rt lives in d_out (consumed by softmax before transpose overwrites out).
    float* Rt = (float*)d_out;

    // ws layout (floats): E at [16257024 .. 32514048); stats after.
    float* wsf = (float*)d_ws;
    float* E  = wsf + 16257024;
    ushort_t* Ahi = (ushort_t*)d_ws;
    ushort_t* Alo = Ahi + (size_t)NB * A_BSTRIDE;
    ushort_t* Bhi = Alo + (size_t)NB * A_BSTRIDE;
    ushort_t* Blo = Bhi + (size_t)NB * B_BSTRIDE;
    float* invn = wsf + 32514048;
    float* mmk = invn + 256;
    float* mmp = mmk + 4096;

    prep_kernel<<<dim3(847), dim3(256), 0, stream>>>(b, mask, invn, mmk, mmp, Bhi, Blo);
    split_kernel<<<dim3(95, 4, 2), dim3(256), 0, stream>>>(b, invn, Ahi, Alo, f, Bhi, Blo);
    gemm_kernel<<<dim3(512), dim3(256), 0, stream>>>(Ahi, Alo, Bhi, Blo, Rt);
    softmax_fused_kernel<<<dim3(63, 9, 4), dim3(256), 0, stream>>>(Rt, mmk, mmp, E);
    transpose_kernel<<<dim3(63, 16, 4), dim3(256), 0, stream>>>(E, out);
}

// Round 15
// 273.840 us; speedup vs baseline: 1.0881x; 1.0881x over previous
//
#include <hip/hip_runtime.h>
#include <math.h>

#define NB 4
#define NC 64
#define NL 1024   // 32x32 kernel-patch grid
#define NP 3969   // 63x63 correlation positions
#define PHW 63

typedef unsigned short ushort_t;
typedef __attribute__((ext_vector_type(8))) short short8;
typedef __attribute__((ext_vector_type(16))) float floatx16;

// A' per b: 32 rtiles * 64 kchunks * 64 lanes * 8 = 2^20 ushorts
#define A_BSTRIDE 1048576
// B' per b: 128 rtiles (4096 rows, padded for 256-wide p-tiles) * 64 * 512
#define B_BSTRIDE 4194304

// ---------------- kernel 1: fused prep = norm + stats + padB --------------
__global__ __launch_bounds__(256) void prep_kernel(const float* __restrict__ bsrc,
                                                   const float* __restrict__ mask,
                                                   float* __restrict__ invn,
                                                   float* __restrict__ mmk,
                                                   float* __restrict__ mmp,
                                                   ushort_t* __restrict__ Bhi,
                                                   ushort_t* __restrict__ Blo) {
    int blk = blockIdx.x;
    if (blk < 256) {
        const float* src = bsrc + (size_t)blk * 4096;
        float s = 0.f;
        for (int i = threadIdx.x; i < 4096; i += 256) { float v = src[i]; s += v * v; }
#pragma unroll
        for (int off = 32; off > 0; off >>= 1) s += __shfl_down(s, off, 64);
        __shared__ float part[4];
        if ((threadIdx.x & 63) == 0) part[threadIdx.x >> 6] = s;
        __syncthreads();
        if (threadIdx.x == 0) {
            float t = part[0] + part[1] + part[2] + part[3];
            invn[blk] = 1.0f / sqrtf(t + 1e-8f);
        }
    } else if (blk < 335) {
        int id = (blk - 256) * 256 + threadIdx.x;
        if (id < NB * NL) {
            int b = id >> 10, l = id & 1023;
            int lh = l >> 5, lw = l & 31;
            const float* m = mask + b * 4096;
            float s = 0.f;
#pragma unroll
            for (int i = 0; i < 4; ++i) {
                int r = min(max(2 * lh - 1 + i, 0), 63);
#pragma unroll
                for (int j = 0; j < 4; ++j) {
                    int c = min(max(2 * lw - 1 + j, 0), 63);
                    s += 1.0f - m[r * 64 + c];
                }
            }
            mmk[id] = s * (1.0f / 16.0f);
        } else {
            int id2 = id - NB * NL;
            if (id2 < NB * NP) {
                int b = id2 / NP, p = id2 - b * NP;
                int ph = p / PHW, pw = p - ph * PHW;
                const float* m = mask + b * 4096;
                float s = 0.f;
#pragma unroll
                for (int i = 0; i < 4; ++i) {
                    int r = min(max(ph - 1 + i, 0), 63);
#pragma unroll
                    for (int j = 0; j < 4; ++j) {
                        int c = min(max(pw - 1 + j, 0), 63);
                        s += 1.0f - m[r * 64 + c];
                    }
                }
                mmp[id2] = s * (1.0f / 16.0f);
            }
        }
    } else {
        // zero rtiles 124..127 (rows 3968..4095) for all b, both matrices
        int idx = (blk - 335) * 256 + threadIdx.x;   // 0..131071
        int b = idx >> 15;
        int r = idx & 32767;
        int mat = r >> 14;
        int o = r & 16383;
        ushort_t* base = (mat ? Blo : Bhi) + (size_t)b * B_BSTRIDE + 124 * 32768;
        uint4 z = {0u, 0u, 0u, 0u};
        ((uint4*)base)[o] = z;
    }
}

// ------------- split helper: fp32 -> bf16 hi + bf16 residual --------------
__device__ inline void split_bf16(float v, ushort_t& hv, ushort_t& lv) {
    unsigned u = __float_as_uint(v);
    unsigned rr = u + 0x7FFFu + ((u >> 16) & 1u);
    hv = (ushort_t)(rr >> 16);
    float fh = __uint_as_float(((unsigned)hv) << 16);
    float remv = v - fh;
    unsigned u2 = __float_as_uint(remv);
    unsigned rr2 = u2 + 0x7FFFu + ((u2 >> 16) & 1u);
    lv = (ushort_t)(rr2 >> 16);
}

// fragment-order address for (row, kchunk)
__device__ inline int frag_addr(int row, int kc) {
    return ((row >> 5) * 64 + kc) * 512 + (row & 31) * 8;
}

// --------- kernel 3: merged splitA (x<32) + splitB (x>=32) ---------------
__global__ __launch_bounds__(256) void split_kernel(const float* __restrict__ bsrc,
                                                    const float* __restrict__ invn,
                                                    ushort_t* __restrict__ Ahi,
                                                    ushort_t* __restrict__ Alo,
                                                    const float* __restrict__ fsrc,
                                                    ushort_t* __restrict__ Bhi,
                                                    ushort_t* __restrict__ Blo) {
    __shared__ float fl[32 * 257];
    int x = blockIdx.x, b = blockIdx.y, chalf = blockIdx.z;
    int t = threadIdx.x;
    if (x < 32) {
        int lh = x;
#pragma unroll
        for (int q = 0; q < 32; ++q) {
            int idx = t + (q << 8);
            int cl = idx >> 8, rem = idx & 255;
            int i = rem >> 6, s = rem & 63;
            int c = (chalf << 5) + cl;
            int r = min(max(2 * lh - 1 + i, 0), 63);
            fl[cl * 257 + rem] = bsrc[(((size_t)((b << 6) + c)) << 12) + (r << 6) + s];
        }
        __syncthreads();
        ushort_t* Ah = Ahi + (size_t)b * A_BSTRIDE;
        ushort_t* Al = Alo + (size_t)b * A_BSTRIDE;
#pragma unroll
        for (int q = 0; q < 4; ++q) {
            int pair = t + (q << 8);         // 0..1023
            int lw = pair & 31, cl = pair >> 5;
            int c = (chalf << 5) + cl;
            float scale = invn[(b << 6) + c];
            const float* row = fl + cl * 257;
            __align__(16) ushort_t h[16];
            __align__(16) ushort_t lo[16];
#pragma unroll
            for (int i = 0; i < 4; ++i)
#pragma unroll
                for (int j = 0; j < 4; ++j) {
                    int s = min(max(2 * lw - 1 + j, 0), 63);
                    split_bf16(row[i * 64 + s] * scale, h[i * 4 + j], lo[i * 4 + j]);
                }
            int a = (lh * 64 + c) * 512 + lw * 8;
            *(uint4*)(Ah + a)       = *(uint4*)h;
            *(uint4*)(Ah + a + 256) = *(uint4*)(h + 8);
            *(uint4*)(Al + a)       = *(uint4*)lo;
            *(uint4*)(Al + a + 256) = *(uint4*)(lo + 8);
        }
    } else {
        int ph = x - 32;
#pragma unroll
        for (int q = 0; q < 32; ++q) {
            int idx = t + (q << 8);
            int cl = idx >> 8, rem = idx & 255;
            int i = rem >> 6, s = rem & 63;
            int c = (chalf << 5) + cl;
            int r = min(max(ph - 1 + i, 0), 63);
            fl[cl * 257 + rem] = fsrc[(((size_t)((b << 6) + c)) << 12) + (r << 6) + s];
        }
        __syncthreads();
        ushort_t* Bh = Bhi + (size_t)b * B_BSTRIDE;
        ushort_t* Bl = Blo + (size_t)b * B_BSTRIDE;
#pragma unroll
        for (int q = 0; q < 8; ++q) {
            int pair = t + (q << 8);          // 0..2047
            int pw = pair & 63, cl = pair >> 6;
            if (pw < PHW) {
                int c = (chalf << 5) + cl;
                const float* row = fl + cl * 257;
                __align__(16) ushort_t h[16];
                __align__(16) ushort_t lo[16];
#pragma unroll
                for (int i = 0; i < 4; ++i)
#pragma unroll
                    for (int j = 0; j < 4; ++j) {
                        int s = min(max(pw - 1 + j, 0), 63);
                        split_bf16(row[i * 64 + s], h[i * 4 + j], lo[i * 4 + j]);
                    }
                int p = ph * PHW + pw;
                int a = frag_addr(p, c);
                *(uint4*)(Bh + a)       = *(uint4*)h;
                *(uint4*)(Bh + a + 256) = *(uint4*)(h + 8);
                *(uint4*)(Bl + a)       = *(uint4*)lo;
                *(uint4*)(Bl + a + 256) = *(uint4*)(lo + 8);
            }
        }
    }
}

// ------------- kernel 4: 128x256-tile, 4-wave, 2-blocks/CU GEMM -----------
// (unchanged control: 51% MfmaUtil, ~90 us)
__global__ __launch_bounds__(256, 2) void gemm_kernel(
    const ushort_t* __restrict__ Ahi, const ushort_t* __restrict__ Alo,
    const ushort_t* __restrict__ Bhi, const ushort_t* __restrict__ Blo,
    float* __restrict__ Rt) {
    // [buf][12288 elems]: Ahi(4x512) Alo(4x512) Bhi(8x512) Blo(8x512) = 24KB
    __shared__ ushort_t smem[2][12288];
    int tid = threadIdx.x;
    int lane = tid & 63, w = tid >> 6;         // w = 0..3 (p-wave)
    int bid = blockIdx.x;                      // 0..511
    int wid = ((bid & 7) << 6) + (bid >> 3);   // bijective XCD-chunk remap
    int b = wid >> 7;
    int rem = wid & 127;
    int lg = rem >> 4;                         // 0..7  : L0 = lg*128
    int pg = rem & 15;                         // 0..15 : P0 = pg*256
    int L0 = lg << 7, P0 = pg << 8;

    // stage roles: 24 segments of 512 elems per chunk, wave w owns 6.
    const ushort_t* segp[6];
    int seg0 = w * 6;
#pragma unroll
    for (int i = 0; i < 6; ++i) {
        int seg = seg0 + i;
        const ushort_t* base;
        int rt;
        if (seg < 4)       { base = Ahi + (size_t)b * A_BSTRIDE + (size_t)(lg << 2) * 32768; rt = seg; }
        else if (seg < 8)  { base = Alo + (size_t)b * A_BSTRIDE + (size_t)(lg << 2) * 32768; rt = seg - 4; }
        else if (seg < 16) { base = Bhi + (size_t)b * B_BSTRIDE + (size_t)(pg << 3) * 32768; rt = seg - 8; }
        else               { base = Blo + (size_t)b * B_BSTRIDE + (size_t)(pg << 3) * 32768; rt = seg - 16; }
        segp[i] = base + (size_t)rt * 32768 + (size_t)(lane << 3);
    }
    int dst0 = seg0 * 512;                     // wave-uniform LDS elem offset

    ushort_t* buf0 = smem[0];
    ushort_t* buf1 = smem[1];

#define STAGE(dstp, kc)                                                                    \
    do {                                                                                   \
        _Pragma("unroll")                                                                  \
        for (int i = 0; i < 6; ++i)                                                        \
            __builtin_amdgcn_global_load_lds(                                              \
                (const __attribute__((address_space(1))) void*)(segp[i] + (size_t)(kc) * 512), \
                (__attribute__((address_space(3))) void*)((dstp) + dst0 + i * 512),        \
                16, 0, 0);                                                                 \
    } while (0)

    floatx16 acc[2][4];
#pragma unroll
    for (int i = 0; i < 2; ++i)
#pragma unroll
        for (int j = 0; j < 4; ++j)
#pragma unroll
            for (int r = 0; r < 16; ++r) acc[i][j][r] = 0.f;

    STAGE(buf0, 0);
    ushort_t* cur = buf0;
    ushort_t* nxt = buf1;

    int boff0 = 4096 + (w << 1) * 512;         // Bhi rtile base for this wave

    for (int t = 0; t < 64; ++t) {
        asm volatile("" ::: "memory");
        __builtin_amdgcn_s_barrier();            // B1: all reads of buf[nxt] done
        asm volatile("" ::: "memory");
        if (t < 63) {
            STAGE(nxt, t + 1);                   // 6 loads into the freed buffer
            asm volatile("s_waitcnt vmcnt(6)" ::: "memory");   // chunk t landed
        } else {
            asm volatile("s_waitcnt vmcnt(0)" ::: "memory");
        }
        __builtin_amdgcn_s_barrier();            // B2: chunk t visible to all
        asm volatile("" ::: "memory");

        const ushort_t* rb = cur + (lane << 3);
        short8 ah[4], al[4], bh[2], bl[2];
#pragma unroll
        for (int lt = 0; lt < 4; ++lt) {
            ah[lt] = *(const short8*)(rb + lt * 512);
            al[lt] = *(const short8*)(rb + 2048 + lt * 512);
        }
#pragma unroll
        for (int pt = 0; pt < 2; ++pt) {
            bh[pt] = *(const short8*)(rb + boff0 + pt * 512);
            bl[pt] = *(const short8*)(rb + 4096 + boff0 + pt * 512);
        }
        __builtin_amdgcn_s_setprio(1);
#pragma unroll
        for (int pt = 0; pt < 2; ++pt)
#pragma unroll
            for (int lt = 0; lt < 4; ++lt) {
                acc[pt][lt] = __builtin_amdgcn_mfma_f32_32x32x16_bf16(bh[pt], ah[lt], acc[pt][lt], 0, 0, 0);
                acc[pt][lt] = __builtin_amdgcn_mfma_f32_32x32x16_bf16(bh[pt], al[lt], acc[pt][lt], 0, 0, 0);
                acc[pt][lt] = __builtin_amdgcn_mfma_f32_32x32x16_bf16(bl[pt], ah[lt], acc[pt][lt], 0, 0, 0);
            }
        __builtin_amdgcn_s_setprio(0);
        ushort_t* tmp = cur; cur = nxt; nxt = tmp;
    }
#undef STAGE

    int x = lane & 31, kg = lane >> 5;
    int pw0 = P0 + (w << 6);
#pragma unroll
    for (int pt = 0; pt < 2; ++pt)
#pragma unroll
        for (int lt = 0; lt < 4; ++lt)
#pragma unroll
            for (int r = 0; r < 16; ++r) {
                int p = pw0 + (pt << 5) + (r & 3) + ((r >> 2) << 3) + (kg << 2);
                int l = L0 + (lt << 5) + x;
                if (p < NP) Rt[((size_t)b * NP + p) * NL + l] = acc[pt][lt][r];
            }
}

// ---------------- kernel 5a: diag1 pass, D1[q] = BUILD(q) -----------------
// Per-q blocks (narrow concurrent window -> L3-resident Rt). Bit-identical
// arithmetic to the verified BUILD macro.
__global__ __launch_bounds__(256) void diag1_kernel(const float* __restrict__ Rt,
                                                    float* __restrict__ D1) {
    int q = blockIdx.x, b = blockIdx.y;
    int l0 = threadIdx.x << 2;
    const float* base = Rt + ((size_t)b * NP + q) * NL;
    float4 r = *(const float4*)(base + l0);
    if (q > 0) {
        const float* pm = base - NL;
        r.x += (l0 > 0) ? pm[l0 - 1] : 0.f;
        r.y += pm[l0];  r.z += pm[l0 + 1];  r.w += pm[l0 + 2];
    }
    if (q < NP - 1) {
        const float* pp = base + NL;
        r.x += pp[l0 + 1];  r.y += pp[l0 + 2];  r.z += pp[l0 + 3];
        r.w += (l0 + 4 < NL) ? pp[l0 + 4] : 0.f;
    }
    *(float4*)(D1 + ((size_t)b * NP + q) * NL + l0) = r;
}

// ------- kernel 5b: diag2-combine + mask + softmax from D1 rows -----------
// Per-p blocks (same grid that proved L3-friendly); reads exactly 3 D1 rows
// directly from global (no LDS staging). Shift indices verbatim from the
// verified kernel; per-element add order unchanged -> absmax unchanged.
__global__ __launch_bounds__(256) void softmax_kernel(const float* __restrict__ D1,
                                                      const float* __restrict__ mmkA,
                                                      const float* __restrict__ mmpA,
                                                      float* __restrict__ E) {
    __shared__ float red[8];
    int p = blockIdx.x, b = blockIdx.y;
    int ph = p / PHW, pw = p - ph * PHW;
    int t = threadIdx.x;
    int lane = t & 63, w = t >> 6;
    int l0 = t << 2;

    bool okm = (p != 0), okp = (p != 3968);
    int Pm = (ph > 0) ? p - 63 : 3905 + pw;
    int Pp = (ph < 62) ? p + 63 : pw + 1;

    const float* Db = D1 + (size_t)b * NP * NL;
    const float* r0 = Db + (size_t)p * NL;
    float4 vc = *(const float4*)(r0 + l0);
    float4 vm = {0.f, 0.f, 0.f, 0.f}, vp = {0.f, 0.f, 0.f, 0.f};
    if (okm) {
        const float* r1 = Db + (size_t)Pm * NL;
        if (l0 >= 32) vm = *(const float4*)(r1 + l0 - 32);
        else {
            vm.x = (l0 == 0) ? 0.f : r1[l0 + 991];
            vm.y = r1[l0 + 992];
            vm.z = r1[l0 + 993];
            vm.w = r1[l0 + 994];
        }
    }
    if (okp) {
        const float* r2 = Db + (size_t)Pp * NL;
        if (l0 < 992) vp = *(const float4*)(r2 + l0 + 32);
        else {
            vp.x = r2[l0 - 991];
            vp.y = r2[l0 - 990];
            vp.z = r2[l0 - 989];
            vp.w = (l0 + 3 == 1023) ? 0.f : r2[l0 - 988];
        }
    }
    float mmpv = mmpA[b * NP + p];
    float4 km = *(const float4*)(mmkA + b * NL + l0);
    float lg[4];
    float fsum[4] = {vc.x + vm.x + vp.x, vc.y + vm.y + vp.y,
                     vc.z + vm.z + vp.z, vc.w + vm.w + vp.w};
    float kk[4] = {km.x, km.y, km.z, km.w};
#pragma unroll
    for (int i = 0; i < 4; ++i) {
        float mmv = (((kk[i] > mmpv) && (mmpv > 0.5f)) || (kk[i] == 1.0f)) ? 1.0f : 0.0f;
        lg[i] = fsum[i] * mmv * 10.0f;
    }
    float mx = fmaxf(fmaxf(lg[0], lg[1]), fmaxf(lg[2], lg[3]));
#pragma unroll
    for (int off = 32; off >= 1; off >>= 1) mx = fmaxf(mx, __shfl_xor(mx, off, 64));
    if (lane == 0) red[w] = mx;
    __syncthreads();
    mx = fmaxf(fmaxf(red[0], red[1]), fmaxf(red[2], red[3]));
    float e[4];
    float s = 0.f;
#pragma unroll
    for (int i = 0; i < 4; ++i) { e[i] = expf(lg[i] - mx); s += e[i]; }
#pragma unroll
    for (int off = 32; off >= 1; off >>= 1) s += __shfl_xor(s, off, 64);
    if (lane == 0) red[4 + w] = s;
    __syncthreads();
    float rinv = 1.0f / (red[4] + red[5] + red[6] + red[7]);
    float4 ev = {e[0] * rinv, e[1] * rinv, e[2] * rinv, e[3] * rinv};
    *(float4*)(E + (((size_t)b * NP + p) << 10) + l0) = ev;
}

// ---------------- kernel 6: tiled transpose E[p][l] -> out[l][p] ----------
__global__ __launch_bounds__(256) void transpose_kernel(const float* __restrict__ E,
                                                        float* __restrict__ out) {
    __shared__ float tile[63 * 65];
    int pt = blockIdx.x;       // 0..62 : p0 = pt*63
    int lt = blockIdx.y;       // 0..15 : l0 = lt*64
    int b  = blockIdx.z;
    int t = threadIdx.x;
    int p0 = pt * 63, l0 = lt << 6;
    const float* Eb = E + ((size_t)b * NP << 10);
    {
        int j = t & 63, i4 = t >> 6;
#pragma unroll
        for (int k = 0; k < 16; ++k) {
            int i = (k << 2) + i4;
            if (i < 63) tile[i * 65 + j] = Eb[((size_t)(p0 + i) << 10) + l0 + j];
        }
    }
    __syncthreads();
    {
        int ii = t & 63, jj4 = t >> 6;
        if (ii < 63) {
#pragma unroll
            for (int k = 0; k < 16; ++k) {
                int jj = (k << 2) + jj4;
                out[((size_t)b * NL + l0 + jj) * NP + p0 + ii] = tile[ii * 65 + jj];
            }
        }
    }
}

extern "C" void kernel_launch(void* const* d_in, const int* in_sizes, int n_in,
                              void* d_out, int out_size, void* d_ws, size_t ws_size,
                              hipStream_t stream) {
    const float* f    = (const float*)d_in[0];
    const float* b    = (const float*)d_in[1];
    const float* mask = (const float*)d_in[2];
    float* out = (float*)d_out;

    // Rt lives in d_out (consumed by diag1 before transpose overwrites out).
    float* Rt = (float*)d_out;

    // ws layout (floats):
    //   D1 at [0 .. 16257024)            — overlays dead A'/B' region post-GEMM
    //   E  at [16257024 .. 32514048)
    //   invn/mmk/mmp after E.
    float* wsf = (float*)d_ws;
    float* D1 = wsf;
    float* E  = wsf + 16257024;
    ushort_t* Ahi = (ushort_t*)d_ws;
    ushort_t* Alo = Ahi + (size_t)NB * A_BSTRIDE;
    ushort_t* Bhi = Alo + (size_t)NB * A_BSTRIDE;
    ushort_t* Blo = Bhi + (size_t)NB * B_BSTRIDE;
    float* invn = wsf + 32514048;
    float* mmk = invn + 256;
    float* mmp = mmk + 4096;

    prep_kernel<<<dim3(847), dim3(256), 0, stream>>>(b, mask, invn, mmk, mmp, Bhi, Blo);
    split_kernel<<<dim3(95, 4, 2), dim3(256), 0, stream>>>(b, invn, Ahi, Alo, f, Bhi, Blo);
    gemm_kernel<<<dim3(512), dim3(256), 0, stream>>>(Ahi, Alo, Bhi, Blo, Rt);
    diag1_kernel<<<dim3(3969, 4), dim3(256), 0, stream>>>(Rt, D1);
    softmax_kernel<<<dim3(3969, 4), dim3(256), 0, stream>>>(D1, mmk, mmp, E);
    transpose_kernel<<<dim3(63, 16, 4), dim3(256), 0, stream>>>(E, out);
}

// Round 17
// 260.364 us; speedup vs baseline: 1.1444x; 1.0518x over previous
//
#include <hip/hip_runtime.h>
#include <math.h>

#define NB 4
#define NC 64
#define NL 1024   // 32x32 kernel-patch grid
#define NP 3969   // 63x63 correlation positions
#define PHW 63

typedef unsigned short ushort_t;
typedef __attribute__((ext_vector_type(8))) short short8;
typedef __attribute__((ext_vector_type(16))) float floatx16;

// A' per b: 32 rtiles * 64 kchunks * 64 lanes * 8 = 2^20 ushorts
#define A_BSTRIDE 1048576
// B' per b: 128 rtiles (4096 rows, padded for 256-wide p-tiles) * 64 * 512
#define B_BSTRIDE 4194304

// ---------------- kernel 1: fused prep = norm + stats + padB --------------
__global__ __launch_bounds__(256) void prep_kernel(const float* __restrict__ bsrc,
                                                   const float* __restrict__ mask,
                                                   float* __restrict__ invn,
                                                   float* __restrict__ mmk,
                                                   float* __restrict__ mmp,
                                                   ushort_t* __restrict__ Bhi,
                                                   ushort_t* __restrict__ Blo) {
    int blk = blockIdx.x;
    if (blk < 256) {
        const float* src = bsrc + (size_t)blk * 4096;
        float s = 0.f;
        for (int i = threadIdx.x; i < 4096; i += 256) { float v = src[i]; s += v * v; }
#pragma unroll
        for (int off = 32; off > 0; off >>= 1) s += __shfl_down(s, off, 64);
        __shared__ float part[4];
        if ((threadIdx.x & 63) == 0) part[threadIdx.x >> 6] = s;
        __syncthreads();
        if (threadIdx.x == 0) {
            float t = part[0] + part[1] + part[2] + part[3];
            invn[blk] = 1.0f / sqrtf(t + 1e-8f);
        }
    } else if (blk < 335) {
        int id = (blk - 256) * 256 + threadIdx.x;
        if (id < NB * NL) {
            int b = id >> 10, l = id & 1023;
            int lh = l >> 5, lw = l & 31;
            const float* m = mask + b * 4096;
            float s = 0.f;
#pragma unroll
            for (int i = 0; i < 4; ++i) {
                int r = min(max(2 * lh - 1 + i, 0), 63);
#pragma unroll
                for (int j = 0; j < 4; ++j) {
                    int c = min(max(2 * lw - 1 + j, 0), 63);
                    s += 1.0f - m[r * 64 + c];
                }
            }
            mmk[id] = s * (1.0f / 16.0f);
        } else {
            int id2 = id - NB * NL;
            if (id2 < NB * NP) {
                int b = id2 / NP, p = id2 - b * NP;
                int ph = p / PHW, pw = p - ph * PHW;
                const float* m = mask + b * 4096;
                float s = 0.f;
#pragma unroll
                for (int i = 0; i < 4; ++i) {
                    int r = min(max(ph - 1 + i, 0), 63);
#pragma unroll
                    for (int j = 0; j < 4; ++j) {
                        int c = min(max(pw - 1 + j, 0), 63);
                        s += 1.0f - m[r * 64 + c];
                    }
                }
                mmp[id2] = s * (1.0f / 16.0f);
            }
        }
    } else {
        // zero rtiles 124..127 (rows 3968..4095) for all b, both matrices
        int idx = (blk - 335) * 256 + threadIdx.x;   // 0..131071
        int b = idx >> 15;
        int r = idx & 32767;
        int mat = r >> 14;
        int o = r & 16383;
        ushort_t* base = (mat ? Blo : Bhi) + (size_t)b * B_BSTRIDE + 124 * 32768;
        uint4 z = {0u, 0u, 0u, 0u};
        ((uint4*)base)[o] = z;
    }
}

// ------------- split helper: fp32 -> bf16 hi + bf16 residual --------------
__device__ inline void split_bf16(float v, ushort_t& hv, ushort_t& lv) {
    unsigned u = __float_as_uint(v);
    unsigned rr = u + 0x7FFFu + ((u >> 16) & 1u);
    hv = (ushort_t)(rr >> 16);
    float fh = __uint_as_float(((unsigned)hv) << 16);
    float remv = v - fh;
    unsigned u2 = __float_as_uint(remv);
    unsigned rr2 = u2 + 0x7FFFu + ((u2 >> 16) & 1u);
    lv = (ushort_t)(rr2 >> 16);
}

// fragment-order address for (row, kchunk)
__device__ inline int frag_addr(int row, int kc) {
    return ((row >> 5) * 64 + kc) * 512 + (row & 31) * 8;
}

// --------- kernel 3: merged splitA (x<32) + splitB (x>=32) ---------------
__global__ __launch_bounds__(256) void split_kernel(const float* __restrict__ bsrc,
                                                    const float* __restrict__ invn,
                                                    ushort_t* __restrict__ Ahi,
                                                    ushort_t* __restrict__ Alo,
                                                    const float* __restrict__ fsrc,
                                                    ushort_t* __restrict__ Bhi,
                                                    ushort_t* __restrict__ Blo) {
    __shared__ float fl[32 * 257];
    int x = blockIdx.x, b = blockIdx.y, chalf = blockIdx.z;
    int t = threadIdx.x;
    if (x < 32) {
        int lh = x;
#pragma unroll
        for (int q = 0; q < 32; ++q) {
            int idx = t + (q << 8);
            int cl = idx >> 8, rem = idx & 255;
            int i = rem >> 6, s = rem & 63;
            int c = (chalf << 5) + cl;
            int r = min(max(2 * lh - 1 + i, 0), 63);
            fl[cl * 257 + rem] = bsrc[(((size_t)((b << 6) + c)) << 12) + (r << 6) + s];
        }
        __syncthreads();
        ushort_t* Ah = Ahi + (size_t)b * A_BSTRIDE;
        ushort_t* Al = Alo + (size_t)b * A_BSTRIDE;
#pragma unroll
        for (int q = 0; q < 4; ++q) {
            int pair = t + (q << 8);         // 0..1023
            int lw = pair & 31, cl = pair >> 5;
            int c = (chalf << 5) + cl;
            float scale = invn[(b << 6) + c];
            const float* row = fl + cl * 257;
            __align__(16) ushort_t h[16];
            __align__(16) ushort_t lo[16];
#pragma unroll
            for (int i = 0; i < 4; ++i)
#pragma unroll
                for (int j = 0; j < 4; ++j) {
                    int s = min(max(2 * lw - 1 + j, 0), 63);
                    split_bf16(row[i * 64 + s] * scale, h[i * 4 + j], lo[i * 4 + j]);
                }
            int a = (lh * 64 + c) * 512 + lw * 8;
            *(uint4*)(Ah + a)       = *(uint4*)h;
            *(uint4*)(Ah + a + 256) = *(uint4*)(h + 8);
            *(uint4*)(Al + a)       = *(uint4*)lo;
            *(uint4*)(Al + a + 256) = *(uint4*)(lo + 8);
        }
    } else {
        int ph = x - 32;
#pragma unroll
        for (int q = 0; q < 32; ++q) {
            int idx = t + (q << 8);
            int cl = idx >> 8, rem = idx & 255;
            int i = rem >> 6, s = rem & 63;
            int c = (chalf << 5) + cl;
            int r = min(max(ph - 1 + i, 0), 63);
            fl[cl * 257 + rem] = fsrc[(((size_t)((b << 6) + c)) << 12) + (r << 6) + s];
        }
        __syncthreads();
        ushort_t* Bh = Bhi + (size_t)b * B_BSTRIDE;
        ushort_t* Bl = Blo + (size_t)b * B_BSTRIDE;
#pragma unroll
        for (int q = 0; q < 8; ++q) {
            int pair = t + (q << 8);          // 0..2047
            int pw = pair & 63, cl = pair >> 6;
            if (pw < PHW) {
                int c = (chalf << 5) + cl;
                const float* row = fl + cl * 257;
                __align__(16) ushort_t h[16];
                __align__(16) ushort_t lo[16];
#pragma unroll
                for (int i = 0; i < 4; ++i)
#pragma unroll
                    for (int j = 0; j < 4; ++j) {
                        int s = min(max(pw - 1 + j, 0), 63);
                        split_bf16(row[i * 64 + s], h[i * 4 + j], lo[i * 4 + j]);
                    }
                int p = ph * PHW + pw;
                int a = frag_addr(p, c);
                *(uint4*)(Bh + a)       = *(uint4*)h;
                *(uint4*)(Bh + a + 256) = *(uint4*)(h + 8);
                *(uint4*)(Bl + a)       = *(uint4*)lo;
                *(uint4*)(Bl + a + 256) = *(uint4*)(lo + 8);
            }
        }
    }
}

// ---- kernel 4: 128x256-tile, 4-wave GEMM; A via LDS, B global->regs ------
// B fragments are wave-private (each wave owns a 64p strip) so they skip LDS
// entirely: 4 dwordx4 global loads per chunk, register double-buffered one
// chunk ahead (latency hides under previous chunk's MFMAs). Only A (shared
// by all 4 waves) is LDS-staged: 8 segs x 1KB dbuf = 16 KB. Per-chunk LDS
// traffic 144->72 KB, ds_reads 12->8. vmcnt(6) counted (T4), raw barriers,
// setprio (T5), XCD swizzle (T1). Per-acc MFMA chain order unchanged
// (reorder is across independent accumulators only) -> bit-identical.
__global__ __launch_bounds__(256, 2) void gemm_kernel(
    const ushort_t* __restrict__ Ahi, const ushort_t* __restrict__ Alo,
    const ushort_t* __restrict__ Bhi, const ushort_t* __restrict__ Blo,
    float* __restrict__ Rt) {
    __shared__ ushort_t smem[2][8][512];       // [buf][seg: 0-3 Ahi rt, 4-7 Alo rt][512]
    int tid = threadIdx.x;
    int lane = tid & 63, w = tid >> 6;         // w = 0..3 (p-wave)
    int bid = blockIdx.x;                      // 0..511
    int wid = ((bid & 7) << 6) + (bid >> 3);   // bijective XCD-chunk remap
    int b = wid >> 7;
    int rem = wid & 127;
    int lg = rem >> 4;                         // 0..7  : L0 = lg*128
    int pg = rem & 15;                         // 0..15 : P0 = pg*256
    int L0 = lg << 7, P0 = pg << 8;

    // A staging sources: wave w stages segs {2w, 2w+1}
    const ushort_t* asrc[2];
#pragma unroll
    for (int i = 0; i < 2; ++i) {
        int s = 2 * w + i;
        const ushort_t* base = ((s >> 2) ? Alo : Ahi) + (size_t)b * A_BSTRIDE;
        asrc[i] = base + (size_t)((L0 >> 5) + (s & 3)) * 32768 + (size_t)(lane << 3);
    }
    ushort_t* dst0 = &smem[0][2 * w][0];
    ushort_t* dst1 = &smem[1][2 * w][0];

    // B direct-load sources: [0]=Bhi pt0, [1]=Bhi pt1, [2]=Blo pt0, [3]=Blo pt1
    const ushort_t* bsrc[4];
#pragma unroll
    for (int i = 0; i < 4; ++i) {
        const ushort_t* base = ((i >> 1) ? Blo : Bhi) + (size_t)b * B_BSTRIDE;
        bsrc[i] = base + (size_t)((P0 >> 5) + 2 * w + (i & 1)) * 32768 + (size_t)(lane << 3);
    }

#define STAGEA(dstp, kc)                                                                   \
    do {                                                                                   \
        _Pragma("unroll")                                                                  \
        for (int i = 0; i < 2; ++i)                                                        \
            __builtin_amdgcn_global_load_lds(                                              \
                (const __attribute__((address_space(1))) void*)(asrc[i] + (size_t)(kc) * 512), \
                (__attribute__((address_space(3))) void*)((dstp) + i * 512),               \
                16, 0, 0);                                                                 \
    } while (0)

#define LOADB(dst, kc)                                                    \
    do {                                                                  \
        _Pragma("unroll")                                                 \
        for (int i = 0; i < 4; ++i)                                       \
            dst[i] = *(const short8*)(bsrc[i] + (size_t)(kc) * 512);      \
    } while (0)

#define COMP(bufi, bf)                                                                     \
    do {                                                                                   \
        _Pragma("unroll")                                                                  \
        for (int lt = 0; lt < 4; ++lt) {                                                   \
            short8 ahf = *(const short8*)(&smem[bufi][lt][lane << 3]);                     \
            short8 alf = *(const short8*)(&smem[bufi][4 + lt][lane << 3]);                 \
            __builtin_amdgcn_s_setprio(1);                                                 \
            _Pragma("unroll")                                                              \
            for (int pt = 0; pt < 2; ++pt) {                                               \
                acc[pt][lt] = __builtin_amdgcn_mfma_f32_32x32x16_bf16(bf[pt], ahf, acc[pt][lt], 0, 0, 0);     \
                acc[pt][lt] = __builtin_amdgcn_mfma_f32_32x32x16_bf16(bf[pt], alf, acc[pt][lt], 0, 0, 0);     \
                acc[pt][lt] = __builtin_amdgcn_mfma_f32_32x32x16_bf16(bf[2 + pt], ahf, acc[pt][lt], 0, 0, 0); \
            }                                                                              \
            __builtin_amdgcn_s_setprio(0);                                                 \
        }                                                                                  \
    } while (0)

    floatx16 acc[2][4];
#pragma unroll
    for (int i = 0; i < 2; ++i)
#pragma unroll
        for (int j = 0; j < 4; ++j)
#pragma unroll
            for (int r = 0; r < 16; ++r) acc[i][j][r] = 0.f;

    short8 bB0[4], bB1[4];
    LOADB(bB0, 0);                             // chunk 0 B -> regs   (4 vm ops)
    STAGEA(dst0, 0);                           // chunk 0 A -> LDS    (2 vm ops)

    for (int t = 0; t < 64; t += 2) {
        // ---- even chunk t: buf0 / bB0 ----
        LOADB(bB1, t + 1);                     // next B (4)
        STAGEA(dst1, t + 1);                   // next A (2)
        asm volatile("s_waitcnt vmcnt(6)" ::: "memory");   // chunk t landed
        __builtin_amdgcn_s_barrier();
        asm volatile("" ::: "memory");
        COMP(0, bB0);
        asm volatile("" ::: "memory");
        __builtin_amdgcn_s_barrier();
        // ---- odd chunk t+1: buf1 / bB1 ----
        if (t + 2 < 64) {
            LOADB(bB0, t + 2);
            STAGEA(dst0, t + 2);
            asm volatile("s_waitcnt vmcnt(6)" ::: "memory");
        } else {
            asm volatile("s_waitcnt vmcnt(0)" ::: "memory");
        }
        __builtin_amdgcn_s_barrier();
        asm volatile("" ::: "memory");
        COMP(1, bB1);
        asm volatile("" ::: "memory");
        __builtin_amdgcn_s_barrier();
    }
#undef STAGEA
#undef LOADB
#undef COMP

    int x = lane & 31, kg = lane >> 5;
    int pw0 = P0 + (w << 6);
#pragma unroll
    for (int pt = 0; pt < 2; ++pt)
#pragma unroll
        for (int lt = 0; lt < 4; ++lt)
#pragma unroll
            for (int r = 0; r < 16; ++r) {
                int p = pw0 + (pt << 5) + (r & 3) + ((r >> 2) << 3) + (kg << 2);
                int l = L0 + (lt << 5) + x;
                if (p < NP) Rt[((size_t)b * NP + p) * NL + l] = acc[pt][lt][r];
            }
}

// ------- kernel 5: fused diag1 + diag2 + mask + softmax, row output -------
// (reverted to the verified R8 per-p version: best measured non-GEMM config)
__global__ __launch_bounds__(256) void softmax_fused_kernel(const float* __restrict__ Rt,
                                                            const float* __restrict__ mmkA,
                                                            const float* __restrict__ mmpA,
                                                            float* __restrict__ E) {
    __shared__ float ld0[1024], ld1[1024], ld2[1024];
    __shared__ float red[8];
    int p = blockIdx.x, b = blockIdx.y;
    int ph = p / PHW, pw = p - ph * PHW;
    int t = threadIdx.x;
    int lane = t & 63, w = t >> 6;
    int l0 = t << 2;

    bool okm = (p != 0), okp = (p != 3968);
    int Pm = (ph > 0) ? p - 63 : 3905 + pw;
    int Pp = (ph < 62) ? p + 63 : pw + 1;

    const float* Rb = Rt + (size_t)b * NP * NL;
#define BUILD(dst, q)                                                   \
    do {                                                                \
        const float* base = Rb + (size_t)(q) * NL;                      \
        float4 r = *(const float4*)(base + l0);                         \
        if ((q) > 0) {                                                  \
            const float* pm = base - NL;                                \
            r.x += (l0 > 0) ? pm[l0 - 1] : 0.f;                         \
            r.y += pm[l0];  r.z += pm[l0 + 1];  r.w += pm[l0 + 2];      \
        }                                                               \
        if ((q) < NP - 1) {                                             \
            const float* pp = base + NL;                                \
            r.x += pp[l0 + 1];  r.y += pp[l0 + 2];  r.z += pp[l0 + 3];  \
            r.w += (l0 + 4 < NL) ? pp[l0 + 4] : 0.f;                    \
        }                                                               \
        *(float4*)(dst + l0) = r;                                       \
    } while (0)

    BUILD(ld0, p);
    if (okm) BUILD(ld1, Pm);
    if (okp) BUILD(ld2, Pp);
#undef BUILD
    __syncthreads();

    float4 vc = *(const float4*)(ld0 + l0);
    float4 vm = {0.f, 0.f, 0.f, 0.f}, vp = {0.f, 0.f, 0.f, 0.f};
    if (okm) {
        if (l0 >= 32) vm = *(const float4*)(ld1 + l0 - 32);
        else {
            vm.x = (l0 == 0) ? 0.f : ld1[l0 + 991];
            vm.y = ld1[l0 + 992];
            vm.z = ld1[l0 + 993];
            vm.w = ld1[l0 + 994];
        }
    }
    if (okp) {
        if (l0 < 992) vp = *(const float4*)(ld2 + l0 + 32);
        else {
            vp.x = ld2[l0 - 991];
            vp.y = ld2[l0 - 990];
            vp.z = ld2[l0 - 989];
            vp.w = (l0 + 3 == 1023) ? 0.f : ld2[l0 - 988];
        }
    }
    float mmpv = mmpA[b * NP + p];
    float4 km = *(const float4*)(mmkA + b * NL + l0);
    float lg[4];
    float fsum[4] = {vc.x + vm.x + vp.x, vc.y + vm.y + vp.y,
                     vc.z + vm.z + vp.z, vc.w + vm.w + vp.w};
    float kk[4] = {km.x, km.y, km.z, km.w};
#pragma unroll
    for (int i = 0; i < 4; ++i) {
        float mmv = (((kk[i] > mmpv) && (mmpv > 0.5f)) || (kk[i] == 1.0f)) ? 1.0f : 0.0f;
        lg[i] = fsum[i] * mmv * 10.0f;
    }
    float mx = fmaxf(fmaxf(lg[0], lg[1]), fmaxf(lg[2], lg[3]));
#pragma unroll
    for (int off = 32; off >= 1; off >>= 1) mx = fmaxf(mx, __shfl_xor(mx, off, 64));
    if (lane == 0) red[w] = mx;
    __syncthreads();
    mx = fmaxf(fmaxf(red[0], red[1]), fmaxf(red[2], red[3]));
    float e[4];
    float s = 0.f;
#pragma unroll
    for (int i = 0; i < 4; ++i) { e[i] = expf(lg[i] - mx); s += e[i]; }
#pragma unroll
    for (int off = 32; off >= 1; off >>= 1) s += __shfl_xor(s, off, 64);
    if (lane == 0) red[4 + w] = s;
    __syncthreads();
    float rinv = 1.0f / (red[4] + red[5] + red[6] + red[7]);
    float4 ev = {e[0] * rinv, e[1] * rinv, e[2] * rinv, e[3] * rinv};
    *(float4*)(E + (((size_t)b * NP + p) << 10) + l0) = ev;
}

// ---------------- kernel 6: tiled transpose E[p][l] -> out[l][p] ----------
__global__ __launch_bounds__(256) void transpose_kernel(const float* __restrict__ E,
                                                        float* __restrict__ out) {
    __shared__ float tile[63 * 65];
    int pt = blockIdx.x;       // 0..62 : p0 = pt*63
    int lt = blockIdx.y;       // 0..15 : l0 = lt*64
    int b  = blockIdx.z;
    int t = threadIdx.x;
    int p0 = pt * 63, l0 = lt << 6;
    const float* Eb = E + ((size_t)b * NP << 10);
    {
        int j = t & 63, i4 = t >> 6;
#pragma unroll
        for (int k = 0; k < 16; ++k) {
            int i = (k << 2) + i4;
            if (i < 63) tile[i * 65 + j] = Eb[((size_t)(p0 + i) << 10) + l0 + j];
        }
    }
    __syncthreads();
    {
        int ii = t & 63, jj4 = t >> 6;
        if (ii < 63) {
#pragma unroll
            for (int k = 0; k < 16; ++k) {
                int jj = (k << 2) + jj4;
                out[((size_t)b * NL + l0 + jj) * NP + p0 + ii] = tile[ii * 65 + jj];
            }
        }
    }
}

extern "C" void kernel_launch(void* const* d_in, const int* in_sizes, int n_in,
                              void* d_out, int out_size, void* d_ws, size_t ws_size,
                              hipStream_t stream) {
    const float* f    = (const float*)d_in[0];
    const float* b    = (const float*)d_in[1];
    const float* mask = (const float*)d_in[2];
    float* out = (float*)d_out;

    // Rt lives in d_out (consumed by softmax before transpose overwrites out).
    float* Rt = (float*)d_out;

    // ws layout (floats): E at [16257024 .. 32514048); stats after.
    // A'/B' (~84 MB) occupy ws from 0 but are dead post-GEMM.
    float* wsf = (float*)d_ws;
    float* E  = wsf + 16257024;
    ushort_t* Ahi = (ushort_t*)d_ws;
    ushort_t* Alo = Ahi + (size_t)NB * A_BSTRIDE;
    ushort_t* Bhi = Alo + (size_t)NB * A_BSTRIDE;
    ushort_t* Blo = Bhi + (size_t)NB * B_BSTRIDE;
    float* invn = wsf + 32514048;
    float* mmk = invn + 256;
    float* mmp = mmk + 4096;

    prep_kernel<<<dim3(847), dim3(256), 0, stream>>>(b, mask, invn, mmk, mmp, Bhi, Blo);
    split_kernel<<<dim3(95, 4, 2), dim3(256), 0, stream>>>(b, invn, Ahi, Alo, f, Bhi, Blo);
    gemm_kernel<<<dim3(512), dim3(256), 0, stream>>>(Ahi, Alo, Bhi, Blo, Rt);
    softmax_fused_kernel<<<dim3(3969, 4), dim3(256), 0, stream>>>(Rt, mmk, mmp, E);
    transpose_kernel<<<dim3(63, 16, 4), dim3(256), 0, stream>>>(E, out);
}